// Round 9
// baseline (613.431 us; speedup 1.0000x reference)
//
#include <hip/hip_runtime.h>

// LSTM T=1024, B=2048, INPUT=2, H=64 — MFMA recurrence.
// R8 = R6 config (256 blocks x BB=8, 4 waves, 1 wave/SIMD) with the 8 batches
// split into TWO independent 4-batch pipelines per wave (P0: b0..3, P1: b4..7,
// each 4x column-duplicated). The two dependency chains interleave -> one
// pipeline's ds_read/MFMA/trans latency is hidden under the other's issue.
// VALU trim vs R7: first MFMA uses a persistent ZERO C (no per-step acc-init);
// gx = bias + W_ih.x added post-select only for used cells (24 ops vs 64 fma).
// Numerics: bf16 W_hh, fresh-rounded bf16 h, fp32 c (absmax 4.9e-4 expected).

typedef short bf16x8 __attribute__((ext_vector_type(8)));
typedef float f32x4  __attribute__((ext_vector_type(4)));

constexpr int T_STEPS = 1024;
constexpr int BATCH   = 2048;
constexpr int H       = 64;
constexpr int BB      = 8;      // batch per block (2 pipelines x 4)
constexpr int THREADS = 256;    // 4 waves
constexpr int HSTR    = 80;     // bf16 per batch row (160 B = 40 dwords)

__device__ __forceinline__ unsigned bf16_rn(float f) {
    unsigned u = __float_as_uint(f);
    u += 0x7fffu + ((u >> 16) & 1u);
    return u >> 16;
}
__device__ __forceinline__ float sigm(float v) {
    return __builtin_amdgcn_rcpf(1.0f + __builtin_amdgcn_exp2f(v * -1.44269504f));
}
__device__ __forceinline__ float tanh_(float v) {
    return fmaf(-2.0f, __builtin_amdgcn_rcpf(1.0f + __builtin_amdgcn_exp2f(v * 2.88539008f)), 1.0f);
}
// barrier that does NOT drain vmcnt (keeps x prefetch in flight)
__device__ __forceinline__ void lds_barrier() {
    asm volatile("s_waitcnt lgkmcnt(0)" ::: "memory");
    __builtin_amdgcn_s_barrier();
}

__global__ __launch_bounds__(THREADS, 1) void lstm_mfma8b(
    const float* __restrict__ x,      // (T, B, 2)
    const float* __restrict__ W_ih,   // (256, 2)
    const float* __restrict__ W_hh,   // (256, 64)
    const float* __restrict__ b_ih,   // (256)
    const float* __restrict__ b_hh,   // (256)
    const float* __restrict__ W_fc,   // (1, 64)
    const float* __restrict__ b_fc,   // (1)
    float* __restrict__ out)          // (B, 1)
{
    const int tid  = threadIdx.x;
    const int w    = tid >> 6;        // wave 0..3: h-slice [16w, 16w+16)
    const int lane = tid & 63;
    const int bcol = lane & 15;       // MFMA column
    const int grp  = lane >> 4;       // k-group / D-row group
    const int bloc = bcol & 3;        // batch-in-pipeline (cols 4..15 dup 0..3)
    const int eh   = bcol >> 2;       // which D element this lane activates

    __shared__ __align__(16) unsigned short s_ht[2][BB * HSTR]; // 2 x 1280 B
    __shared__ float s_red[32];

    const int b0 = blockIdx.x * BB;

    // ---- A fragments: gate g tile = W_hh rows [64g+16w, +16), single bf16 -
    // shared by both pipelines (same rows, different B operand)
    bf16x8 Af[4][2];
    #pragma unroll
    for (int g = 0; g < 4; ++g) {
        #pragma unroll
        for (int kk = 0; kk < 2; ++kk) {
            const float* src = W_hh + (64 * g + 16 * w + bcol) * H + kk * 32 + grp * 8;
            #pragma unroll
            for (int j = 0; j < 8; ++j)
                Af[g][kk][j] = (short)bf16_rn(src[j]);
        }
    }

    // ---- gx constants ONLY for this lane's row (g, eh): r = 64g+16w+4grp+eh
    float gbs[4], c0s[4], c1s[4];
    #pragma unroll
    for (int g = 0; g < 4; ++g) {
        const int r = 64 * g + 16 * w + 4 * grp + eh;
        gbs[g] = b_ih[r] + b_hh[r];
        c0s[g] = W_ih[2 * r];
        c1s[g] = W_ih[2 * r + 1];
    }

    // ---- per-lane states: row rbase for batches bloc (P0) and 4+bloc (P1) -
    const int rbase = 16 * w + 4 * grp + eh;
    float csA = 0.f, hvA = 0.f, csB = 0.f, hvB = 0.f;
    const float wfc = W_fc[rbase];

    // persistent zero C for the first MFMA of each chain (never overwritten)
    const f32x4 zero4 = {0.f, 0.f, 0.f, 0.f};

    // zero both h-table buffers (2*8*80 shorts = 640 dwords)
    for (int i = tid; i < 640; i += THREADS)
        reinterpret_cast<unsigned*>(s_ht)[i] = 0;

    // ---- x: depth-3 register prefetch, one float2 per pipeline ------------
    const float* xbA = x + (b0 + bloc) * 2;
    const float* xbB = x + (b0 + 4 + bloc) * 2;
    float2 xcA  = *reinterpret_cast<const float2*>(xbA);
    float2 xn1A = *reinterpret_cast<const float2*>(xbA + 1 * BATCH * 2);
    float2 xn2A = *reinterpret_cast<const float2*>(xbA + 2 * BATCH * 2);
    float2 xcB  = *reinterpret_cast<const float2*>(xbB);
    float2 xn1B = *reinterpret_cast<const float2*>(xbB + 1 * BATCH * 2);
    float2 xn2B = *reinterpret_cast<const float2*>(xbB + 2 * BATCH * 2);

    __syncthreads();   // one full barrier (init visible)

    // initial B fragments from buf 0 (h = 0); single b128 per kk per pipeline
    bf16x8 BfA[2], BfB[2];
    #pragma unroll
    for (int kk = 0; kk < 2; ++kk) {
        BfA[kk] = *reinterpret_cast<const bf16x8*>(
                      &s_ht[0][bloc * HSTR + kk * 32 + grp * 8]);
        BfB[kk] = *reinterpret_cast<const bf16x8*>(
                      &s_ht[0][(4 + bloc) * HSTR + kk * 32 + grp * 8]);
    }

    #pragma unroll 2
    for (int s = 0; s < T_STEPS; ++s) {
        // issue next x loads FIRST (complete ~3 steps later; never drained)
        const int sn = (s + 3 < T_STEPS) ? s + 3 : T_STEPS - 1;
        const float2 xfA = *reinterpret_cast<const float2*>(xbA + sn * BATCH * 2);
        const float2 xfB = *reinterpret_cast<const float2*>(xbB + sn * BATCH * 2);

        // --- two independent MFMA chains (C = persistent zero) -------------
        f32x4 accA[4], accB[4];
        #pragma unroll
        for (int g = 0; g < 4; ++g)
            accA[g] = __builtin_amdgcn_mfma_f32_16x16x32_bf16(Af[g][0], BfA[0], zero4, 0, 0, 0);
        #pragma unroll
        for (int g = 0; g < 4; ++g)
            accB[g] = __builtin_amdgcn_mfma_f32_16x16x32_bf16(Af[g][0], BfB[0], zero4, 0, 0, 0);
        #pragma unroll
        for (int g = 0; g < 4; ++g)
            accA[g] = __builtin_amdgcn_mfma_f32_16x16x32_bf16(Af[g][1], BfA[1], accA[g], 0, 0, 0);
        #pragma unroll
        for (int g = 0; g < 4; ++g)
            accB[g] = __builtin_amdgcn_mfma_f32_16x16x32_bf16(Af[g][1], BfB[1], accB[g], 0, 0, 0);

        // --- pipeline A: select + gx + activations + c/h -------------------
        {
            float p[4];
            #pragma unroll
            for (int g = 0; g < 4; ++g) {
                const float v01 = (eh & 1) ? accA[g][1] : accA[g][0];
                const float v23 = (eh & 1) ? accA[g][3] : accA[g][2];
                const float sel = (eh & 2) ? v23 : v01;
                p[g] = fmaf(c1s[g], xcA.y, fmaf(c0s[g], xcA.x, gbs[g])) + sel;
            }
            const float iv = sigm(p[0]), fv = sigm(p[1]);
            const float gv = tanh_(p[2]), ov = sigm(p[3]);
            csA = fmaf(fv, csA, iv * gv);
            hvA = ov * tanh_(csA);
            s_ht[(s + 1) & 1][bloc * HSTR + rbase] = (unsigned short)bf16_rn(hvA);
        }
        // --- pipeline B --------------------------------------------------
        {
            float p[4];
            #pragma unroll
            for (int g = 0; g < 4; ++g) {
                const float v01 = (eh & 1) ? accB[g][1] : accB[g][0];
                const float v23 = (eh & 1) ? accB[g][3] : accB[g][2];
                const float sel = (eh & 2) ? v23 : v01;
                p[g] = fmaf(c1s[g], xcB.y, fmaf(c0s[g], xcB.x, gbs[g])) + sel;
            }
            const float iv = sigm(p[0]), fv = sigm(p[1]);
            const float gv = tanh_(p[2]), ov = sigm(p[3]);
            csB = fmaf(fv, csB, iv * gv);
            hvB = ov * tanh_(csB);
            s_ht[(s + 1) & 1][(4 + bloc) * HSTR + rbase] = (unsigned short)bf16_rn(hvB);
        }

        // rotate x prefetch (depth 3)
        xcA = xn1A; xn1A = xn2A; xn2A = xfA;
        xcB = xn1B; xn1B = xn2B; xn2B = xfB;

        lds_barrier();   // lgkmcnt(0) + s_barrier; vmem stays in flight

        // B fragments for next step (2-way banked b128, free)
        #pragma unroll
        for (int kk = 0; kk < 2; ++kk) {
            BfA[kk] = *reinterpret_cast<const bf16x8*>(
                          &s_ht[(s + 1) & 1][bloc * HSTR + kk * 32 + grp * 8]);
            BfB[kk] = *reinterpret_cast<const bf16x8*>(
                          &s_ht[(s + 1) & 1][(4 + bloc) * HSTR + kk * 32 + grp * 8]);
        }
    }

    // ---- fused fc epilogue ----------------------------------------------
    float vA = hvA * wfc;
    float vB = hvB * wfc;
    #pragma unroll
    for (int off = 4; off <= 32; off <<= 1) {
        vA += __shfl_xor(vA, off);   // sum over eh (4,8) and grp (16,32)
        vB += __shfl_xor(vB, off);
    }
    if (lane < 4) {
        s_red[w * 8 + lane]     = vA;   // batch b0 + lane
        s_red[w * 8 + 4 + lane] = vB;   // batch b0 + 4 + lane
    }
    __syncthreads();
    if (tid < 8) {
        out[b0 + tid] = s_red[tid] + s_red[8 + tid] + s_red[16 + tid]
                      + s_red[24 + tid] + b_fc[0];
    }
}

extern "C" void kernel_launch(void* const* d_in, const int* in_sizes, int n_in,
                              void* d_out, int out_size, void* d_ws, size_t ws_size,
                              hipStream_t stream) {
    const float* x    = (const float*)d_in[0];
    const float* W_ih = (const float*)d_in[1];
    const float* W_hh = (const float*)d_in[2];
    const float* b_ih = (const float*)d_in[3];
    const float* b_hh = (const float*)d_in[4];
    const float* W_fc = (const float*)d_in[5];
    const float* b_fc = (const float*)d_in[6];
    float* out = (float*)d_out;

    dim3 grid(BATCH / BB);   // 256 blocks -> all 256 CUs
    dim3 block(THREADS);     // 4 waves
    lstm_mfma8b<<<grid, block, 0, stream>>>(x, W_ih, W_hh, b_ih, b_hh, W_fc, b_fc, out);
}

// Round 10
// 417.700 us; speedup vs baseline: 1.4686x; 1.4686x over previous
//
#include <hip/hip_runtime.h>

// LSTM T=1024, B=2048, INPUT=2, H=64 — MFMA recurrence.
// R9 = R6 config (256 blocks x BB=8, 4 waves, 2x col-dup, 1 wave/SIMD, single
// bf16 W_hh, lds_barrier, HSTR=80) + VALU-issue cuts:
//  1. paired reciprocals: sigma/tanh denominators combined, 10 rcp -> 6 rcp
//     per lane/step (exact to ~2ulp).
//  2. v_cvt_pk_bf16_f32 packs both h values in ONE instruction.
//  3. next-step acc init (gx) moved between h-write and barrier (fills the
//     barrier-arrival gap; post-barrier path is ds_read -> MFMA directly).
// Model: period ~= VALU-busy + ~430 invariant exposure; cuts target VALU-busy.

typedef short bf16x8 __attribute__((ext_vector_type(8)));
typedef float f32x4  __attribute__((ext_vector_type(4)));

constexpr int T_STEPS = 1024;
constexpr int BATCH   = 2048;
constexpr int H       = 64;
constexpr int BB      = 8;      // batch per block
constexpr int THREADS = 256;    // 4 waves
constexpr int HSTR    = 80;     // bf16 per batch row (160 B = 40 dwords)

__device__ __forceinline__ unsigned bf16_rn(float f) {
    unsigned u = __float_as_uint(f);
    u += 0x7fffu + ((u >> 16) & 1u);
    return u >> 16;
}
__device__ __forceinline__ float rcp_(float v)  { return __builtin_amdgcn_rcpf(v); }
__device__ __forceinline__ float exp2_(float v) { return __builtin_amdgcn_exp2f(v); }
// barrier that does NOT drain vmcnt (keeps x prefetch in flight)
__device__ __forceinline__ void lds_barrier() {
    asm volatile("s_waitcnt lgkmcnt(0)" ::: "memory");
    __builtin_amdgcn_s_barrier();
}

__global__ __launch_bounds__(THREADS, 1) void lstm_mfma9(
    const float* __restrict__ x,      // (T, B, 2)
    const float* __restrict__ W_ih,   // (256, 2)
    const float* __restrict__ W_hh,   // (256, 64)
    const float* __restrict__ b_ih,   // (256)
    const float* __restrict__ b_hh,   // (256)
    const float* __restrict__ W_fc,   // (1, 64)
    const float* __restrict__ b_fc,   // (1)
    float* __restrict__ out)          // (B, 1)
{
    const int tid  = threadIdx.x;
    const int w    = tid >> 6;        // wave 0..3: h-slice [16w, 16w+16)
    const int lane = tid & 63;
    const int bcol = lane & 15;       // MFMA column
    const int grp  = lane >> 4;       // k-group / D-row group
    const int bloc = bcol & 7;        // real batch column (cols 8..15 duplicate)
    const bool elo = (bcol < 8);      // lane activates D elements {0,1} vs {2,3}

    __shared__ __align__(16) unsigned short s_ht[2][BB * HSTR]; // 2 x 1280 B
    __shared__ float s_red[32];

    const int b0 = blockIdx.x * BB;

    // ---- A fragments: gate g tile = W_hh rows [64g+16w, +16), single bf16 -
    bf16x8 Af[4][2];
    #pragma unroll
    for (int g = 0; g < 4; ++g) {
        #pragma unroll
        for (int kk = 0; kk < 2; ++kk) {
            const float* src = W_hh + (64 * g + 16 * w + bcol) * H + kk * 32 + grp * 8;
            #pragma unroll
            for (int j = 0; j < 8; ++j)
                Af[g][kk][j] = (short)bf16_rn(src[j]);
        }
    }

    // ---- gx constants: D row (gate g) = 64g + 16w + 4grp + e --------------
    float gb[4][4], c0_[4][4], c1_[4][4];
    #pragma unroll
    for (int g = 0; g < 4; ++g)
        #pragma unroll
        for (int e = 0; e < 4; ++e) {
            const int r = 64 * g + 16 * w + 4 * grp + e;
            gb[g][e]  = b_ih[r] + b_hh[r];
            c0_[g][e] = W_ih[2 * r];
            c1_[g][e] = W_ih[2 * r + 1];
        }

    // ---- per-lane state: rows rbase, rbase+1 of batch b0+bloc -------------
    const int rbase = 16 * w + 4 * grp + (elo ? 0 : 2);
    float cs0 = 0.f, cs1 = 0.f, hv0 = 0.f, hv1 = 0.f;
    const float wfc0 = W_fc[rbase];
    const float wfc1 = W_fc[rbase + 1];

    // zero both h-table buffers (2*8*80 shorts = 640 dwords)
    for (int i = tid; i < 640; i += THREADS)
        reinterpret_cast<unsigned*>(s_ht)[i] = 0;

    // ---- x: depth-3 register prefetch (dup lanes load same addr) ----------
    const float* xb = x + (b0 + bloc) * 2;
    float2 xc  = *reinterpret_cast<const float2*>(xb);
    float2 xn1 = *reinterpret_cast<const float2*>(xb + 1 * BATCH * 2);
    float2 xn2 = *reinterpret_cast<const float2*>(xb + 2 * BATCH * 2);

    __syncthreads();   // full barrier once (init visible)

    // initial B fragments from buf 0 (h = 0); single b128 per kk
    bf16x8 Bf[2];
    #pragma unroll
    for (int kk = 0; kk < 2; ++kk)
        Bf[kk] = *reinterpret_cast<const bf16x8*>(
                     &s_ht[0][bloc * HSTR + kk * 32 + grp * 8]);

    // acc for step 0: C = gx folded in (all 16 cells valid for this bcol)
    f32x4 acc[4];
    #pragma unroll
    for (int g = 0; g < 4; ++g)
        #pragma unroll
        for (int e = 0; e < 4; ++e)
            acc[g][e] = fmaf(c1_[g][e], xc.y, fmaf(c0_[g][e], xc.x, gb[g][e]));

    constexpr float L1 = -1.44269504f;   // -log2(e)
    constexpr float L2 =  2.88539008f;   //  2 log2(e)

    #pragma unroll 2
    for (int s = 0; s < T_STEPS; ++s) {
        // issue next x load FIRST (completes ~3 steps later; never drained)
        const int sn = (s + 3 < T_STEPS) ? s + 3 : T_STEPS - 1;
        const float2 xf = *reinterpret_cast<const float2*>(xb + sn * BATCH * 2);

        // recurrent GEMM: 4 gate-chains of 2 dependent MFMAs (C = gx)
        #pragma unroll
        for (int kk = 0; kk < 2; ++kk)
            #pragma unroll
            for (int g = 0; g < 4; ++g)
                acc[g] = __builtin_amdgcn_mfma_f32_16x16x32_bf16(Af[g][kk], Bf[kk], acc[g], 0, 0, 0);

        // select this lane's 2 states (cols duplicated -> both halves valid)
        float p[4], q[4];
        #pragma unroll
        for (int g = 0; g < 4; ++g) {
            p[g] = elo ? acc[g][0] : acc[g][2];
            q[g] = elo ? acc[g][1] : acc[g][3];
        }

        // activations with paired reciprocals (3 rcp per state instead of 5)
        {
            const float ei = exp2_(p[0] * L1), ef = exp2_(p[1] * L1);
            const float eg = exp2_(p[2] * L2), eo = exp2_(p[3] * L1);
            const float ai = 1.f + ei, af = 1.f + ef;
            const float ag = 1.f + eg, ao = 1.f + eo;
            const float rif = rcp_(ai * af);          // 1/((1+ei)(1+ef))
            const float si = rif * af, sf = rif * ai; // sigm(i), sigm(f)
            const float rgo = rcp_(ag * ao);
            const float tg = fmaf(-2.f, rgo * ao, 1.f); // tanh(g)
            const float so = rgo * ag;                  // sigm(o)
            cs0 = fmaf(sf, cs0, si * tg);
            const float ec = exp2_(cs0 * L2);
            hv0 = so * fmaf(-2.f, rcp_(1.f + ec), 1.f);
        }
        {
            const float ei = exp2_(q[0] * L1), ef = exp2_(q[1] * L1);
            const float eg = exp2_(q[2] * L2), eo = exp2_(q[3] * L1);
            const float ai = 1.f + ei, af = 1.f + ef;
            const float ag = 1.f + eg, ao = 1.f + eo;
            const float rif = rcp_(ai * af);
            const float si = rif * af, sf = rif * ai;
            const float rgo = rcp_(ag * ao);
            const float tg = fmaf(-2.f, rgo * ao, 1.f);
            const float so = rgo * ag;
            cs1 = fmaf(sf, cs1, si * tg);
            const float ec = exp2_(cs1 * L2);
            hv1 = so * fmaf(-2.f, rcp_(1.f + ec), 1.f);
        }

        // pack both h -> bf16 pair in ONE instruction, write next-parity table
        {
            unsigned pk;
            asm("v_cvt_pk_bf16_f32 %0, %1, %2" : "=v"(pk) : "v"(hv0), "v"(hv1));
            *reinterpret_cast<unsigned*>(
                &s_ht[(s + 1) & 1][bloc * HSTR + rbase]) = pk;
        }

        // rotate x prefetch (depth 3)
        xc = xn1; xn1 = xn2; xn2 = xf;

        // init acc for NEXT step now (fills the barrier-arrival gap; the
        // post-barrier critical path is then ds_read -> MFMA directly)
        #pragma unroll
        for (int g = 0; g < 4; ++g)
            #pragma unroll
            for (int e = 0; e < 4; ++e)
                acc[g][e] = fmaf(c1_[g][e], xc.y, fmaf(c0_[g][e], xc.x, gb[g][e]));

        lds_barrier();   // lgkmcnt(0) + s_barrier; vmem stays in flight

        // B fragments for next step: b128 quads tile banks exactly 2-way
        #pragma unroll
        for (int kk = 0; kk < 2; ++kk)
            Bf[kk] = *reinterpret_cast<const bf16x8*>(
                         &s_ht[(s + 1) & 1][bloc * HSTR + kk * 32 + grp * 8]);
    }

    // ---- fused fc epilogue ----------------------------------------------
    float v = fmaf(hv0, wfc0, hv1 * wfc1);
    v += __shfl_xor(v, 8);    // combine e{0,1} / e{2,3} halves (same batch)
    v += __shfl_xor(v, 16);   // combine grp
    v += __shfl_xor(v, 32);
    if (lane < 8) s_red[w * 8 + lane] = v;
    __syncthreads();
    if (tid < 8) {
        out[b0 + tid] = s_red[tid] + s_red[8 + tid] + s_red[16 + tid]
                      + s_red[24 + tid] + b_fc[0];
    }
}

extern "C" void kernel_launch(void* const* d_in, const int* in_sizes, int n_in,
                              void* d_out, int out_size, void* d_ws, size_t ws_size,
                              hipStream_t stream) {
    const float* x    = (const float*)d_in[0];
    const float* W_ih = (const float*)d_in[1];
    const float* W_hh = (const float*)d_in[2];
    const float* b_ih = (const float*)d_in[3];
    const float* b_hh = (const float*)d_in[4];
    const float* W_fc = (const float*)d_in[5];
    const float* b_fc = (const float*)d_in[6];
    float* out = (float*)d_out;

    dim3 grid(BATCH / BB);   // 256 blocks -> all 256 CUs
    dim3 block(THREADS);     // 4 waves
    lstm_mfma9<<<grid, block, 0, stream>>>(x, W_ih, W_hh, b_ih, b_hh, W_fc, b_fc, out);
}

// Round 11
// 369.609 us; speedup vs baseline: 1.6597x; 1.1301x over previous
//
#include <hip/hip_runtime.h>

// LSTM T=1024, B=2048, INPUT=2, H=64 — MFMA recurrence.
// R10 = R6 config (256 blocks x BB=8, 4 waves, 2x col-dup, 1 wave/SIMD, single
// bf16 W_hh, lds_barrier, HSTR=80, depth-3 x prefetch) + two clean VALU cuts:
//  1. paired reciprocals: sigmoid/tanh denominators share rcp (10 -> 6 rcp).
//  2. zero-C MFMA + gx post-select: first MFMA uses hoisted zero C (ready at
//     barrier exit -> post-barrier chain is ds_read -> MFMA directly); gx is
//     computed only for the 8 used (gate,state) cells (16 fma + 8 add vs 32 fma).
// NO inline-asm cvt_pk (R9's regression: opaque asm blocked scheduling, m240).

typedef short bf16x8 __attribute__((ext_vector_type(8)));
typedef float f32x4  __attribute__((ext_vector_type(4)));

constexpr int T_STEPS = 1024;
constexpr int BATCH   = 2048;
constexpr int H       = 64;
constexpr int BB      = 8;      // batch per block
constexpr int THREADS = 256;    // 4 waves
constexpr int HSTR    = 80;     // bf16 per batch row (160 B = 40 dwords)

__device__ __forceinline__ unsigned bf16_rn(float f) {
    unsigned u = __float_as_uint(f);
    u += 0x7fffu + ((u >> 16) & 1u);
    return u >> 16;
}
__device__ __forceinline__ float rcp_(float v)  { return __builtin_amdgcn_rcpf(v); }
__device__ __forceinline__ float exp2_(float v) { return __builtin_amdgcn_exp2f(v); }
// barrier that does NOT drain vmcnt (keeps x prefetch in flight)
__device__ __forceinline__ void lds_barrier() {
    asm volatile("s_waitcnt lgkmcnt(0)" ::: "memory");
    __builtin_amdgcn_s_barrier();
}

__global__ __launch_bounds__(THREADS, 1) void lstm_mfma10(
    const float* __restrict__ x,      // (T, B, 2)
    const float* __restrict__ W_ih,   // (256, 2)
    const float* __restrict__ W_hh,   // (256, 64)
    const float* __restrict__ b_ih,   // (256)
    const float* __restrict__ b_hh,   // (256)
    const float* __restrict__ W_fc,   // (1, 64)
    const float* __restrict__ b_fc,   // (1)
    float* __restrict__ out)          // (B, 1)
{
    const int tid  = threadIdx.x;
    const int w    = tid >> 6;        // wave 0..3: h-slice [16w, 16w+16)
    const int lane = tid & 63;
    const int bcol = lane & 15;       // MFMA column
    const int grp  = lane >> 4;       // k-group / D-row group
    const int bloc = bcol & 7;        // real batch column (cols 8..15 duplicate)
    const bool elo = (bcol < 8);      // lane activates D elements {0,1} vs {2,3}

    __shared__ __align__(16) unsigned short s_ht[2][BB * HSTR]; // 2 x 1280 B
    __shared__ float s_red[32];

    const int b0 = blockIdx.x * BB;

    // ---- A fragments: gate g tile = W_hh rows [64g+16w, +16), single bf16 -
    bf16x8 Af[4][2];
    #pragma unroll
    for (int g = 0; g < 4; ++g) {
        #pragma unroll
        for (int kk = 0; kk < 2; ++kk) {
            const float* src = W_hh + (64 * g + 16 * w + bcol) * H + kk * 32 + grp * 8;
            #pragma unroll
            for (int j = 0; j < 8; ++j)
                Af[g][kk][j] = (short)bf16_rn(src[j]);
        }
    }

    // ---- per-lane state rows: rbase (state0), rbase+1 (state1) ------------
    const int rbase = 16 * w + 4 * grp + (elo ? 0 : 2);   // h-index
    float cs0 = 0.f, cs1 = 0.f, hv0 = 0.f, hv1 = 0.f;
    const float wfc0 = W_fc[rbase];
    const float wfc1 = W_fc[rbase + 1];

    // ---- gx constants ONLY for the 8 used (gate, state) rows --------------
    float gba[4], c0a[4], c1a[4];     // state0: row 64g + rbase
    float gbb[4], c0b[4], c1b[4];     // state1: row 64g + rbase + 1
    #pragma unroll
    for (int g = 0; g < 4; ++g) {
        const int r0 = 64 * g + rbase;
        gba[g] = b_ih[r0] + b_hh[r0];
        c0a[g] = W_ih[2 * r0];
        c1a[g] = W_ih[2 * r0 + 1];
        const int r1 = r0 + 1;
        gbb[g] = b_ih[r1] + b_hh[r1];
        c0b[g] = W_ih[2 * r1];
        c1b[g] = W_ih[2 * r1 + 1];
    }

    // hoisted zero C for the first MFMA of each chain
    const f32x4 zero4 = {0.f, 0.f, 0.f, 0.f};

    // zero both h-table buffers (2*8*80 shorts = 640 dwords)
    for (int i = tid; i < 640; i += THREADS)
        reinterpret_cast<unsigned*>(s_ht)[i] = 0;

    // ---- x: depth-3 register prefetch (dup lanes load same addr) ----------
    const float* xb = x + (b0 + bloc) * 2;
    float2 xc  = *reinterpret_cast<const float2*>(xb);
    float2 xn1 = *reinterpret_cast<const float2*>(xb + 1 * BATCH * 2);
    float2 xn2 = *reinterpret_cast<const float2*>(xb + 2 * BATCH * 2);

    __syncthreads();   // full barrier once (init visible)

    // initial B fragments from buf 0 (h = 0); single b128 per kk
    bf16x8 Bf[2];
    #pragma unroll
    for (int kk = 0; kk < 2; ++kk)
        Bf[kk] = *reinterpret_cast<const bf16x8*>(
                     &s_ht[0][bloc * HSTR + kk * 32 + grp * 8]);

    constexpr float L1 = -1.44269504f;   // -log2(e)
    constexpr float L2 =  2.88539008f;   //  2 log2(e)

    #pragma unroll 2
    for (int s = 0; s < T_STEPS; ++s) {
        // issue next x load FIRST (completes ~3 steps later; never drained)
        const int sn = (s + 3 < T_STEPS) ? s + 3 : T_STEPS - 1;
        const float2 xf = *reinterpret_cast<const float2*>(xb + sn * BATCH * 2);

        // recurrent GEMM: 4 gate-chains of 2 dependent MFMAs, C = zero
        f32x4 acc[4];
        #pragma unroll
        for (int g = 0; g < 4; ++g)
            acc[g] = __builtin_amdgcn_mfma_f32_16x16x32_bf16(Af[g][0], Bf[0], zero4, 0, 0, 0);
        #pragma unroll
        for (int g = 0; g < 4; ++g)
            acc[g] = __builtin_amdgcn_mfma_f32_16x16x32_bf16(Af[g][1], Bf[1], acc[g], 0, 0, 0);

        // select this lane's 2 states + add gx (only 8 used cells)
        float p[4], q[4];
        #pragma unroll
        for (int g = 0; g < 4; ++g) {
            const float sp = elo ? acc[g][0] : acc[g][2];
            const float sq = elo ? acc[g][1] : acc[g][3];
            p[g] = sp + fmaf(c1a[g], xc.y, fmaf(c0a[g], xc.x, gba[g]));
            q[g] = sq + fmaf(c1b[g], xc.y, fmaf(c0b[g], xc.x, gbb[g]));
        }

        // activations with paired reciprocals (3 rcp per state instead of 5)
        {
            const float ei = exp2_(p[0] * L1), ef = exp2_(p[1] * L1);
            const float eg = exp2_(p[2] * L2), eo = exp2_(p[3] * L1);
            const float ai = 1.f + ei, af = 1.f + ef;
            const float ag = 1.f + eg, ao = 1.f + eo;
            const float rif = rcp_(ai * af);            // 1/((1+ei)(1+ef))
            const float si = rif * af, sf = rif * ai;   // sigm(i), sigm(f)
            const float rgo = rcp_(ag * ao);
            const float tg = fmaf(-2.f, rgo * ao, 1.f); // tanh(g)
            const float so = rgo * ag;                  // sigm(o)
            cs0 = fmaf(sf, cs0, si * tg);
            const float ec = exp2_(cs0 * L2);
            hv0 = so * fmaf(-2.f, rcp_(1.f + ec), 1.f);
        }
        {
            const float ei = exp2_(q[0] * L1), ef = exp2_(q[1] * L1);
            const float eg = exp2_(q[2] * L2), eo = exp2_(q[3] * L1);
            const float ai = 1.f + ei, af = 1.f + ef;
            const float ag = 1.f + eg, ao = 1.f + eo;
            const float rif = rcp_(ai * af);
            const float si = rif * af, sf = rif * ai;
            const float rgo = rcp_(ag * ao);
            const float tg = fmaf(-2.f, rgo * ao, 1.f);
            const float so = rgo * ag;
            cs1 = fmaf(sf, cs1, si * tg);
            const float ec = exp2_(cs1 * L2);
            hv1 = so * fmaf(-2.f, rcp_(1.f + ec), 1.f);
        }

        // pack 2 h -> 1 dword (plain ops, compiler-scheduled), write table
        {
            const unsigned pk = bf16_rn(hv0) | (bf16_rn(hv1) << 16);
            *reinterpret_cast<unsigned*>(
                &s_ht[(s + 1) & 1][bloc * HSTR + rbase]) = pk;
        }

        // rotate x prefetch (depth 3)
        xc = xn1; xn1 = xn2; xn2 = xf;

        lds_barrier();   // lgkmcnt(0) + s_barrier; vmem stays in flight

        // B fragments for next step: b128 quads tile banks exactly 2-way
        #pragma unroll
        for (int kk = 0; kk < 2; ++kk)
            Bf[kk] = *reinterpret_cast<const bf16x8*>(
                         &s_ht[(s + 1) & 1][bloc * HSTR + kk * 32 + grp * 8]);
    }

    // ---- fused fc epilogue ----------------------------------------------
    float v = fmaf(hv0, wfc0, hv1 * wfc1);
    v += __shfl_xor(v, 8);    // combine e{0,1} / e{2,3} halves (same batch)
    v += __shfl_xor(v, 16);   // combine grp
    v += __shfl_xor(v, 32);
    if (lane < 8) s_red[w * 8 + lane] = v;
    __syncthreads();
    if (tid < 8) {
        out[b0 + tid] = s_red[tid] + s_red[8 + tid] + s_red[16 + tid]
                      + s_red[24 + tid] + b_fc[0];
    }
}

extern "C" void kernel_launch(void* const* d_in, const int* in_sizes, int n_in,
                              void* d_out, int out_size, void* d_ws, size_t ws_size,
                              hipStream_t stream) {
    const float* x    = (const float*)d_in[0];
    const float* W_ih = (const float*)d_in[1];
    const float* W_hh = (const float*)d_in[2];
    const float* b_ih = (const float*)d_in[3];
    const float* b_hh = (const float*)d_in[4];
    const float* W_fc = (const float*)d_in[5];
    const float* b_fc = (const float*)d_in[6];
    float* out = (float*)d_out;

    dim3 grid(BATCH / BB);   // 256 blocks -> all 256 CUs
    dim3 block(THREADS);     // 4 waves
    lstm_mfma10<<<grid, block, 0, stream>>>(x, W_ih, W_hh, b_ih, b_hh, W_fc, b_fc, out);
}